// Round 1
// baseline (1385.601 us; speedup 1.0000x reference)
//
#include <hip/hip_runtime.h>
#include <math.h>

#define N_NODES 32768
#define N_EDGES 491520
#define F_IN    11
#define H       64
#define G_GRAPHS 2048
#define NN_PER_G 16
#define R_REACT 1024
#define L_LAYERS 4
#define EIN     129   // 2H+1
#define NIN     139   // 2H+F
#define EPB     240   // edges per block (64-thread block = 1 wave)
#define NPB     16    // nodes per block

__device__ __forceinline__ float silu_f(float x) {
    return x / (1.0f + __expf(-x));
}

__device__ __forceinline__ void atomAddF(float* p, float v) {
    // maps to global_atomic_add_f32 on gfx950
    unsafeAtomicAdd(p, v);
}

// ---------------- embed: h = h0 @ emb_w + emb_b ; agg = 0 ----------------
__global__ __launch_bounds__(256) void k_embed(
        const float* __restrict__ h0, const float* __restrict__ emb_w,
        const float* __restrict__ emb_b,
        float* __restrict__ h, float* __restrict__ agg) {
    int tid = blockIdx.x * 256 + threadIdx.x;   // N*H threads
    int n = tid >> 6, j = tid & 63;
    float acc = emb_b[j];
#pragma unroll
    for (int k = 0; k < F_IN; ++k)
        acc += h0[n * F_IN + k] * emb_w[k * H + j];
    h[tid] = acc;
    agg[tid] = 0.0f;
}

// ---------------- radial per edge ----------------
__global__ __launch_bounds__(256) void k_radial(
        const int* __restrict__ edges, const float* __restrict__ pos,
        float* __restrict__ radial) {
    int e = blockIdx.x * 256 + threadIdx.x;
    if (e < N_EDGES) {
        int r = edges[e], c = edges[N_EDGES + e];
        float dx = pos[r * 3 + 0] - pos[c * 3 + 0];
        float dy = pos[r * 3 + 1] - pos[c * 3 + 1];
        float dz = pos[r * 3 + 2] - pos[c * 3 + 2];
        radial[e] = dx * dx + dy * dy + dz * dz;
    }
}

// ---------------- fused edge MLP + scatter-add ----------------
// 1 wave per block; weights register-stationary (W1:129 + W2:64 VGPRs);
// 2 edges per pass for two independent FMA chains.
__global__ __launch_bounds__(64, 2) void k_edge(
        const float* __restrict__ h, const float* __restrict__ radial,
        const int* __restrict__ edges, const float* __restrict__ emask,
        const float* __restrict__ W1, const float* __restrict__ b1,
        const float* __restrict__ W2, const float* __restrict__ b2,
        float* __restrict__ agg) {
    const int lane = threadIdx.x;

    float w1r[EIN];
#pragma unroll
    for (int k = 0; k < EIN; ++k) w1r[k] = W1[k * H + lane];
    float w2r[H];
#pragma unroll
    for (int k = 0; k < H; ++k) w2r[k] = W2[k * H + lane];
    const float bias1 = b1[lane], bias2 = b2[lane];

    __shared__ __align__(16) float xb[2][132];  // [h_row | h_col | radial]
    __shared__ __align__(16) float eb[2][64];   // hidden after GEMM1

    const int base = blockIdx.x * EPB;
    for (int p = 0; p < EPB; p += 2) {
        const int e0 = base + p, e1 = e0 + 1;
        const int r0 = edges[e0], c0 = edges[N_EDGES + e0];
        const int r1 = edges[e1], c1 = edges[N_EDGES + e1];
        xb[0][lane]      = h[r0 * H + lane];
        xb[0][64 + lane] = h[c0 * H + lane];
        xb[1][lane]      = h[r1 * H + lane];
        xb[1][64 + lane] = h[c1 * H + lane];
        if (lane == 0) { xb[0][128] = radial[e0]; xb[1][128] = radial[e1]; }
        __syncthreads();

        float a0 = bias1, a1 = bias1;
        const float4* x0 = (const float4*)(&xb[0][0]);
        const float4* x1 = (const float4*)(&xb[1][0]);
#pragma unroll
        for (int m = 0; m < 32; ++m) {
            float4 v0 = x0[m], v1 = x1[m];
            a0 += v0.x * w1r[4 * m + 0]; a1 += v1.x * w1r[4 * m + 0];
            a0 += v0.y * w1r[4 * m + 1]; a1 += v1.y * w1r[4 * m + 1];
            a0 += v0.z * w1r[4 * m + 2]; a1 += v1.z * w1r[4 * m + 2];
            a0 += v0.w * w1r[4 * m + 3]; a1 += v1.w * w1r[4 * m + 3];
        }
        a0 += xb[0][128] * w1r[128];
        a1 += xb[1][128] * w1r[128];
        float s0 = silu_f(a0), s1 = silu_f(a1);
        __syncthreads();
        eb[0][lane] = s0; eb[1][lane] = s1;
        __syncthreads();

        float o0 = bias2, o1 = bias2;
        const float4* q0 = (const float4*)(&eb[0][0]);
        const float4* q1 = (const float4*)(&eb[1][0]);
#pragma unroll
        for (int m = 0; m < 16; ++m) {
            float4 v0 = q0[m], v1 = q1[m];
            o0 += v0.x * w2r[4 * m + 0]; o1 += v1.x * w2r[4 * m + 0];
            o0 += v0.y * w2r[4 * m + 1]; o1 += v1.y * w2r[4 * m + 1];
            o0 += v0.z * w2r[4 * m + 2]; o1 += v1.z * w2r[4 * m + 2];
            o0 += v0.w * w2r[4 * m + 3]; o1 += v1.w * w2r[4 * m + 3];
        }
        o0 = silu_f(o0) * emask[e0];
        o1 = silu_f(o1) * emask[e1];
        atomAddF(&agg[r0 * H + lane], o0);
        atomAddF(&agg[r1 * H + lane], o1);
        __syncthreads();
    }
}

// ---------------- node MLP: h = silu([h,agg,h0]@W1+b1)@W2+b2 ; agg=0 -----
__global__ __launch_bounds__(64, 2) void k_node(
        float* __restrict__ h, float* __restrict__ agg,
        const float* __restrict__ h0,
        const float* __restrict__ W1, const float* __restrict__ b1,
        const float* __restrict__ W2, const float* __restrict__ b2) {
    const int lane = threadIdx.x;

    float w1r[NIN];
#pragma unroll
    for (int k = 0; k < NIN; ++k) w1r[k] = W1[k * H + lane];
    float w2r[H];
#pragma unroll
    for (int k = 0; k < H; ++k) w2r[k] = W2[k * H + lane];
    const float bias1 = b1[lane], bias2 = b2[lane];

    __shared__ __align__(16) float xb[2][140];  // [h | agg | h0]
    __shared__ __align__(16) float tb[2][64];

    const int base = blockIdx.x * NPB;
    for (int p = 0; p < NPB; p += 2) {
        const int n0 = base + p, n1 = n0 + 1;
        xb[0][lane]      = h[n0 * H + lane];
        xb[0][64 + lane] = agg[n0 * H + lane];
        xb[1][lane]      = h[n1 * H + lane];
        xb[1][64 + lane] = agg[n1 * H + lane];
        if (lane < F_IN) {
            xb[0][128 + lane] = h0[n0 * F_IN + lane];
            xb[1][128 + lane] = h0[n1 * F_IN + lane];
        }
        agg[n0 * H + lane] = 0.0f;   // ready for next layer's edge kernel
        agg[n1 * H + lane] = 0.0f;
        __syncthreads();

        float a0 = bias1, a1 = bias1;
        const float4* x0 = (const float4*)(&xb[0][0]);
        const float4* x1 = (const float4*)(&xb[1][0]);
#pragma unroll
        for (int m = 0; m < 34; ++m) {   // 136 of 139
            float4 v0 = x0[m], v1 = x1[m];
            a0 += v0.x * w1r[4 * m + 0]; a1 += v1.x * w1r[4 * m + 0];
            a0 += v0.y * w1r[4 * m + 1]; a1 += v1.y * w1r[4 * m + 1];
            a0 += v0.z * w1r[4 * m + 2]; a1 += v1.z * w1r[4 * m + 2];
            a0 += v0.w * w1r[4 * m + 3]; a1 += v1.w * w1r[4 * m + 3];
        }
#pragma unroll
        for (int k = 136; k < NIN; ++k) {
            a0 += xb[0][k] * w1r[k];
            a1 += xb[1][k] * w1r[k];
        }
        float s0 = silu_f(a0), s1 = silu_f(a1);
        __syncthreads();
        tb[0][lane] = s0; tb[1][lane] = s1;
        __syncthreads();

        float o0 = bias2, o1 = bias2;
        const float4* q0 = (const float4*)(&tb[0][0]);
        const float4* q1 = (const float4*)(&tb[1][0]);
#pragma unroll
        for (int m = 0; m < 16; ++m) {
            float4 v0 = q0[m], v1 = q1[m];
            o0 += v0.x * w2r[4 * m + 0]; o1 += v1.x * w2r[4 * m + 0];
            o0 += v0.y * w2r[4 * m + 1]; o1 += v1.y * w2r[4 * m + 1];
            o0 += v0.z * w2r[4 * m + 2]; o1 += v1.z * w2r[4 * m + 2];
            o0 += v0.w * w2r[4 * m + 3]; o1 += v1.w * w2r[4 * m + 3];
        }
        h[n0 * H + lane] = o0;   // no trailing silu in node model
        h[n1 * H + lane] = o1;
        __syncthreads();
    }
}

// ---------------- node decoder: h = (silu(h@W1+b1)@W2+b2) * node_mask ----
__global__ __launch_bounds__(64, 4) void k_dec(
        float* __restrict__ h, const float* __restrict__ nmask,
        const float* __restrict__ W1, const float* __restrict__ b1,
        const float* __restrict__ W2, const float* __restrict__ b2) {
    const int lane = threadIdx.x;
    float w1r[H], w2r[H];
#pragma unroll
    for (int k = 0; k < H; ++k) w1r[k] = W1[k * H + lane];
#pragma unroll
    for (int k = 0; k < H; ++k) w2r[k] = W2[k * H + lane];
    const float bias1 = b1[lane], bias2 = b2[lane];

    __shared__ __align__(16) float xb[2][64];
    __shared__ __align__(16) float tb[2][64];

    const int base = blockIdx.x * NPB;
    for (int p = 0; p < NPB; p += 2) {
        const int n0 = base + p, n1 = n0 + 1;
        xb[0][lane] = h[n0 * H + lane];
        xb[1][lane] = h[n1 * H + lane];
        __syncthreads();
        float a0 = bias1, a1 = bias1;
        const float4* x0 = (const float4*)(&xb[0][0]);
        const float4* x1 = (const float4*)(&xb[1][0]);
#pragma unroll
        for (int m = 0; m < 16; ++m) {
            float4 v0 = x0[m], v1 = x1[m];
            a0 += v0.x * w1r[4 * m + 0]; a1 += v1.x * w1r[4 * m + 0];
            a0 += v0.y * w1r[4 * m + 1]; a1 += v1.y * w1r[4 * m + 1];
            a0 += v0.z * w1r[4 * m + 2]; a1 += v1.z * w1r[4 * m + 2];
            a0 += v0.w * w1r[4 * m + 3]; a1 += v1.w * w1r[4 * m + 3];
        }
        float s0 = silu_f(a0), s1 = silu_f(a1);
        __syncthreads();
        tb[0][lane] = s0; tb[1][lane] = s1;
        __syncthreads();
        float o0 = bias2, o1 = bias2;
        const float4* q0 = (const float4*)(&tb[0][0]);
        const float4* q1 = (const float4*)(&tb[1][0]);
#pragma unroll
        for (int m = 0; m < 16; ++m) {
            float4 v0 = q0[m], v1 = q1[m];
            o0 += v0.x * w2r[4 * m + 0]; o1 += v1.x * w2r[4 * m + 0];
            o0 += v0.y * w2r[4 * m + 1]; o1 += v1.y * w2r[4 * m + 1];
            o0 += v0.z * w2r[4 * m + 2]; o1 += v1.z * w2r[4 * m + 2];
            o0 += v0.w * w2r[4 * m + 3]; o1 += v1.w * w2r[4 * m + 3];
        }
        h[n0 * H + lane] = o0 * nmask[n0];
        h[n1 * H + lane] = o1 * nmask[n1];
        __syncthreads();
    }
}

// ---------------- pool + graph decoder + signed reaction aggregation -----
__global__ __launch_bounds__(64) void k_graph(
        const float* __restrict__ h, const int* __restrict__ rid,
        const float* __restrict__ rsign,
        const float* __restrict__ W1, const float* __restrict__ b1,
        const float* __restrict__ W2, const float* __restrict__ b2,
        float* __restrict__ pred) {
    const int g = blockIdx.x;
    const int lane = threadIdx.x;
    float hgv = 0.0f;
#pragma unroll
    for (int m = 0; m < NN_PER_G; ++m)
        hgv += h[(g * NN_PER_G + m) * H + lane];
    __shared__ __align__(16) float hgs[64];
    hgs[lane] = hgv;
    __syncthreads();
    float acc = b1[lane];
#pragma unroll
    for (int k = 0; k < H; ++k)
        acc += hgs[k] * W1[k * H + lane];
    float part = silu_f(acc) * W2[lane];
#pragma unroll
    for (int off = 32; off > 0; off >>= 1)
        part += __shfl_down(part, off);
    if (lane == 0)
        atomAddF(&pred[rid[g]], (part + b2[0]) * rsign[g]);
}

extern "C" void kernel_launch(void* const* d_in, const int* in_sizes, int n_in,
                              void* d_out, int out_size, void* d_ws, size_t ws_size,
                              hipStream_t stream) {
    const float* h0      = (const float*)d_in[0];
    const float* pos     = (const float*)d_in[1];
    const int*   edges   = (const int*)d_in[2];
    const float* nmask   = (const float*)d_in[3];
    const float* emask   = (const float*)d_in[4];
    const int*   rid     = (const int*)d_in[5];
    const float* rsign   = (const float*)d_in[6];
    const float* emb_w   = (const float*)d_in[7];
    const float* emb_b   = (const float*)d_in[8];
    const float* edge_w1 = (const float*)d_in[9];
    const float* edge_b1 = (const float*)d_in[10];
    const float* edge_w2 = (const float*)d_in[11];
    const float* edge_b2 = (const float*)d_in[12];
    const float* node_w1 = (const float*)d_in[13];
    const float* node_b1 = (const float*)d_in[14];
    const float* node_w2 = (const float*)d_in[15];
    const float* node_b2 = (const float*)d_in[16];
    const float* dec_w1  = (const float*)d_in[17];
    const float* dec_b1  = (const float*)d_in[18];
    const float* dec_w2  = (const float*)d_in[19];
    const float* dec_b2  = (const float*)d_in[20];
    const float* g_w1    = (const float*)d_in[21];
    const float* g_b1    = (const float*)d_in[22];
    const float* g_w2    = (const float*)d_in[23];
    const float* g_b2    = (const float*)d_in[24];

    float* h      = (float*)d_ws;            // N*H
    float* agg    = h + N_NODES * H;         // N*H
    float* radial = agg + N_NODES * H;       // E
    float* pred   = (float*)d_out;

    hipMemsetAsync(d_out, 0, R_REACT * sizeof(float), stream);
    k_embed<<<(N_NODES * H) / 256, 256, 0, stream>>>(h0, emb_w, emb_b, h, agg);
    k_radial<<<N_EDGES / 256, 256, 0, stream>>>(edges, pos, radial);

    for (int i = 0; i < L_LAYERS; ++i) {
        k_edge<<<N_EDGES / EPB, 64, 0, stream>>>(
            h, radial, edges, emask,
            edge_w1 + i * EIN * H, edge_b1 + i * H,
            edge_w2 + i * H * H,  edge_b2 + i * H, agg);
        k_node<<<N_NODES / NPB, 64, 0, stream>>>(
            h, agg, h0,
            node_w1 + i * NIN * H, node_b1 + i * H,
            node_w2 + i * H * H,   node_b2 + i * H);
    }
    k_dec<<<N_NODES / NPB, 64, 0, stream>>>(h, nmask, dec_w1, dec_b1, dec_w2, dec_b2);
    k_graph<<<G_GRAPHS, 64, 0, stream>>>(h, rid, rsign, g_w1, g_b1, g_w2, g_b2, pred);
}

// Round 2
// 766.951 us; speedup vs baseline: 1.8066x; 1.8066x over previous
//
#include <hip/hip_runtime.h>
#include <math.h>

#define N_NODES 32768
#define N_EDGES 491520
#define F_IN    11
#define H       64
#define G_GRAPHS 2048
#define NN_PER_G 16
#define R_REACT 1024
#define L_LAYERS 4
#define EIN     129   // 2H+1
#define NIN     139   // 2H+F
#define EPB2    120   // edges per block for k_edge2 (grid 4096)
#define NPB     16    // nodes per block

__device__ __forceinline__ float silu_f(float x) {
    return x / (1.0f + __expf(-x));
}

__device__ __forceinline__ void atomAddF(float* p, float v) {
    unsafeAtomicAdd(p, v);   // global_atomic_add_f32
}

// ---------------- embed: h = h0 @ emb_w + emb_b ; agg = 0 ----------------
__global__ __launch_bounds__(256) void k_embed(
        const float* __restrict__ h0, const float* __restrict__ emb_w,
        const float* __restrict__ emb_b,
        float* __restrict__ h, float* __restrict__ agg) {
    int tid = blockIdx.x * 256 + threadIdx.x;   // N*H threads
    int n = tid >> 6, j = tid & 63;
    float acc = emb_b[j];
#pragma unroll
    for (int k = 0; k < F_IN; ++k)
        acc += h0[n * F_IN + k] * emb_w[k * H + j];
    h[tid] = acc;
    agg[tid] = 0.0f;
}

// ---------------- radial per edge ----------------
__global__ __launch_bounds__(256) void k_radial(
        const int* __restrict__ edges, const float* __restrict__ pos,
        float* __restrict__ radial) {
    int e = blockIdx.x * 256 + threadIdx.x;
    if (e < N_EDGES) {
        int r = edges[e], c = edges[N_EDGES + e];
        float dx = pos[r * 3 + 0] - pos[c * 3 + 0];
        float dy = pos[r * 3 + 1] - pos[c * 3 + 1];
        float dz = pos[r * 3 + 2] - pos[c * 3 + 2];
        radial[e] = dx * dx + dy * dy + dz * dz;
    }
}

// ---------------- node projection: PA = h@W1a + b1 ; PB = h@W1b ----------
// W1a = edge_w1[i][0:64], W1b = edge_w1[i][64:128]  (rows k, cols j)
__global__ __launch_bounds__(64, 2) void k_nodeproj(
        const float* __restrict__ h,
        const float* __restrict__ W1,   // [EIN x H] for this layer
        const float* __restrict__ b1,
        float* __restrict__ PA, float* __restrict__ PB) {
    const int lane = threadIdx.x;
    float w1a[H], w1b[H];
#pragma unroll
    for (int k = 0; k < H; ++k) w1a[k] = W1[k * H + lane];
#pragma unroll
    for (int k = 0; k < H; ++k) w1b[k] = W1[(H + k) * H + lane];
    const float bias1 = b1[lane];

    __shared__ __align__(16) float xb[2][64];

    const int base = blockIdx.x * NPB;
    for (int p = 0; p < NPB; p += 2) {
        const int n0 = base + p, n1 = n0 + 1;
        __syncthreads();
        xb[0][lane] = h[n0 * H + lane];
        xb[1][lane] = h[n1 * H + lane];
        __syncthreads();

        float pa0 = bias1, pb0 = 0.0f, pa1 = bias1, pb1 = 0.0f;
        const float4* x0 = (const float4*)(&xb[0][0]);
        const float4* x1 = (const float4*)(&xb[1][0]);
#pragma unroll
        for (int m = 0; m < 16; ++m) {
            float4 v0 = x0[m], v1 = x1[m];
            pa0 += v0.x * w1a[4 * m + 0]; pb0 += v0.x * w1b[4 * m + 0];
            pa1 += v1.x * w1a[4 * m + 0]; pb1 += v1.x * w1b[4 * m + 0];
            pa0 += v0.y * w1a[4 * m + 1]; pb0 += v0.y * w1b[4 * m + 1];
            pa1 += v1.y * w1a[4 * m + 1]; pb1 += v1.y * w1b[4 * m + 1];
            pa0 += v0.z * w1a[4 * m + 2]; pb0 += v0.z * w1b[4 * m + 2];
            pa1 += v1.z * w1a[4 * m + 2]; pb1 += v1.z * w1b[4 * m + 2];
            pa0 += v0.w * w1a[4 * m + 3]; pb0 += v0.w * w1b[4 * m + 3];
            pa1 += v1.w * w1a[4 * m + 3]; pb1 += v1.w * w1b[4 * m + 3];
        }
        PA[n0 * H + lane] = pa0;
        PB[n0 * H + lane] = pb0;
        PA[n1 * H + lane] = pa1;
        PB[n1 * H + lane] = pb1;
    }
}

// ---------------- edge: silu(PA[r]+PB[c]+radial*w1c) @ W2 -> scatter -----
// GEMM1 eliminated algebraically; only K=64 GEMM2 per edge remains.
__global__ __launch_bounds__(64, 4) void k_edge2(
        const float* __restrict__ PA, const float* __restrict__ PB,
        const float* __restrict__ radial,
        const int* __restrict__ edges, const float* __restrict__ emask,
        const float* __restrict__ W1,   // only row 128 (w1c) used
        const float* __restrict__ W2, const float* __restrict__ b2,
        float* __restrict__ agg) {
    const int lane = threadIdx.x;
    float w2r[H];
#pragma unroll
    for (int k = 0; k < H; ++k) w2r[k] = W2[k * H + lane];
    const float w1c = W1[128 * H + lane];
    const float bias2 = b2[lane];

    __shared__ __align__(16) float eb[2][64];

    const int base = blockIdx.x * EPB2;
    for (int p = 0; p < EPB2; p += 2) {
        const int e0 = base + p, e1 = e0 + 1;
        const int r0 = edges[e0], c0 = edges[N_EDGES + e0];
        const int r1 = edges[e1], c1 = edges[N_EDGES + e1];
        const float rad0 = radial[e0], rad1 = radial[e1];

        float t0 = PA[r0 * H + lane] + PB[c0 * H + lane] + rad0 * w1c;
        float t1 = PA[r1 * H + lane] + PB[c1 * H + lane] + rad1 * w1c;
        float s0 = silu_f(t0), s1 = silu_f(t1);

        __syncthreads();             // protect previous pass's eb reads
        eb[0][lane] = s0; eb[1][lane] = s1;
        __syncthreads();

        float o0 = bias2, o1 = bias2;
        const float4* q0 = (const float4*)(&eb[0][0]);
        const float4* q1 = (const float4*)(&eb[1][0]);
#pragma unroll
        for (int m = 0; m < 16; ++m) {
            float4 v0 = q0[m], v1 = q1[m];
            o0 += v0.x * w2r[4 * m + 0]; o1 += v1.x * w2r[4 * m + 0];
            o0 += v0.y * w2r[4 * m + 1]; o1 += v1.y * w2r[4 * m + 1];
            o0 += v0.z * w2r[4 * m + 2]; o1 += v1.z * w2r[4 * m + 2];
            o0 += v0.w * w2r[4 * m + 3]; o1 += v1.w * w2r[4 * m + 3];
        }
        o0 = silu_f(o0) * emask[e0];
        o1 = silu_f(o1) * emask[e1];
        atomAddF(&agg[r0 * H + lane], o0);
        atomAddF(&agg[r1 * H + lane], o1);
    }
}

// ---------------- node MLP: h = silu([h,agg,h0]@W1+b1)@W2+b2 ; agg=0 -----
__global__ __launch_bounds__(64, 2) void k_node(
        float* __restrict__ h, float* __restrict__ agg,
        const float* __restrict__ h0,
        const float* __restrict__ W1, const float* __restrict__ b1,
        const float* __restrict__ W2, const float* __restrict__ b2) {
    const int lane = threadIdx.x;

    float w1r[NIN];
#pragma unroll
    for (int k = 0; k < NIN; ++k) w1r[k] = W1[k * H + lane];
    float w2r[H];
#pragma unroll
    for (int k = 0; k < H; ++k) w2r[k] = W2[k * H + lane];
    const float bias1 = b1[lane], bias2 = b2[lane];

    __shared__ __align__(16) float xb[2][140];  // [h | agg | h0]
    __shared__ __align__(16) float tb[2][64];

    const int base = blockIdx.x * NPB;
    for (int p = 0; p < NPB; p += 2) {
        const int n0 = base + p, n1 = n0 + 1;
        xb[0][lane]      = h[n0 * H + lane];
        xb[0][64 + lane] = agg[n0 * H + lane];
        xb[1][lane]      = h[n1 * H + lane];
        xb[1][64 + lane] = agg[n1 * H + lane];
        if (lane < F_IN) {
            xb[0][128 + lane] = h0[n0 * F_IN + lane];
            xb[1][128 + lane] = h0[n1 * F_IN + lane];
        }
        agg[n0 * H + lane] = 0.0f;   // ready for next layer's edge kernel
        agg[n1 * H + lane] = 0.0f;
        __syncthreads();

        float a0 = bias1, a1 = bias1;
        const float4* x0 = (const float4*)(&xb[0][0]);
        const float4* x1 = (const float4*)(&xb[1][0]);
#pragma unroll
        for (int m = 0; m < 34; ++m) {   // 136 of 139
            float4 v0 = x0[m], v1 = x1[m];
            a0 += v0.x * w1r[4 * m + 0]; a1 += v1.x * w1r[4 * m + 0];
            a0 += v0.y * w1r[4 * m + 1]; a1 += v1.y * w1r[4 * m + 1];
            a0 += v0.z * w1r[4 * m + 2]; a1 += v1.z * w1r[4 * m + 2];
            a0 += v0.w * w1r[4 * m + 3]; a1 += v1.w * w1r[4 * m + 3];
        }
#pragma unroll
        for (int k = 136; k < NIN; ++k) {
            a0 += xb[0][k] * w1r[k];
            a1 += xb[1][k] * w1r[k];
        }
        float s0 = silu_f(a0), s1 = silu_f(a1);
        __syncthreads();
        tb[0][lane] = s0; tb[1][lane] = s1;
        __syncthreads();

        float o0 = bias2, o1 = bias2;
        const float4* q0 = (const float4*)(&tb[0][0]);
        const float4* q1 = (const float4*)(&tb[1][0]);
#pragma unroll
        for (int m = 0; m < 16; ++m) {
            float4 v0 = q0[m], v1 = q1[m];
            o0 += v0.x * w2r[4 * m + 0]; o1 += v1.x * w2r[4 * m + 0];
            o0 += v0.y * w2r[4 * m + 1]; o1 += v1.y * w2r[4 * m + 1];
            o0 += v0.z * w2r[4 * m + 2]; o1 += v1.z * w2r[4 * m + 2];
            o0 += v0.w * w2r[4 * m + 3]; o1 += v1.w * w2r[4 * m + 3];
        }
        h[n0 * H + lane] = o0;   // no trailing silu in node model
        h[n1 * H + lane] = o1;
        __syncthreads();
    }
}

// ---------------- node decoder: h = (silu(h@W1+b1)@W2+b2) * node_mask ----
__global__ __launch_bounds__(64, 4) void k_dec(
        float* __restrict__ h, const float* __restrict__ nmask,
        const float* __restrict__ W1, const float* __restrict__ b1,
        const float* __restrict__ W2, const float* __restrict__ b2) {
    const int lane = threadIdx.x;
    float w1r[H], w2r[H];
#pragma unroll
    for (int k = 0; k < H; ++k) w1r[k] = W1[k * H + lane];
#pragma unroll
    for (int k = 0; k < H; ++k) w2r[k] = W2[k * H + lane];
    const float bias1 = b1[lane], bias2 = b2[lane];

    __shared__ __align__(16) float xb[2][64];
    __shared__ __align__(16) float tb[2][64];

    const int base = blockIdx.x * NPB;
    for (int p = 0; p < NPB; p += 2) {
        const int n0 = base + p, n1 = n0 + 1;
        xb[0][lane] = h[n0 * H + lane];
        xb[1][lane] = h[n1 * H + lane];
        __syncthreads();
        float a0 = bias1, a1 = bias1;
        const float4* x0 = (const float4*)(&xb[0][0]);
        const float4* x1 = (const float4*)(&xb[1][0]);
#pragma unroll
        for (int m = 0; m < 16; ++m) {
            float4 v0 = x0[m], v1 = x1[m];
            a0 += v0.x * w1r[4 * m + 0]; a1 += v1.x * w1r[4 * m + 0];
            a0 += v0.y * w1r[4 * m + 1]; a1 += v1.y * w1r[4 * m + 1];
            a0 += v0.z * w1r[4 * m + 2]; a1 += v1.z * w1r[4 * m + 2];
            a0 += v0.w * w1r[4 * m + 3]; a1 += v1.w * w1r[4 * m + 3];
        }
        float s0 = silu_f(a0), s1 = silu_f(a1);
        __syncthreads();
        tb[0][lane] = s0; tb[1][lane] = s1;
        __syncthreads();
        float o0 = bias2, o1 = bias2;
        const float4* q0 = (const float4*)(&tb[0][0]);
        const float4* q1 = (const float4*)(&tb[1][0]);
#pragma unroll
        for (int m = 0; m < 16; ++m) {
            float4 v0 = q0[m], v1 = q1[m];
            o0 += v0.x * w2r[4 * m + 0]; o1 += v1.x * w2r[4 * m + 0];
            o0 += v0.y * w2r[4 * m + 1]; o1 += v1.y * w2r[4 * m + 1];
            o0 += v0.z * w2r[4 * m + 2]; o1 += v1.z * w2r[4 * m + 2];
            o0 += v0.w * w2r[4 * m + 3]; o1 += v1.w * w2r[4 * m + 3];
        }
        h[n0 * H + lane] = o0 * nmask[n0];
        h[n1 * H + lane] = o1 * nmask[n1];
        __syncthreads();
    }
}

// ---------------- pool + graph decoder + signed reaction aggregation -----
__global__ __launch_bounds__(64) void k_graph(
        const float* __restrict__ h, const int* __restrict__ rid,
        const float* __restrict__ rsign,
        const float* __restrict__ W1, const float* __restrict__ b1,
        const float* __restrict__ W2, const float* __restrict__ b2,
        float* __restrict__ pred) {
    const int g = blockIdx.x;
    const int lane = threadIdx.x;
    float hgv = 0.0f;
#pragma unroll
    for (int m = 0; m < NN_PER_G; ++m)
        hgv += h[(g * NN_PER_G + m) * H + lane];
    __shared__ __align__(16) float hgs[64];
    hgs[lane] = hgv;
    __syncthreads();
    float acc = b1[lane];
#pragma unroll
    for (int k = 0; k < H; ++k)
        acc += hgs[k] * W1[k * H + lane];
    float part = silu_f(acc) * W2[lane];
#pragma unroll
    for (int off = 32; off > 0; off >>= 1)
        part += __shfl_down(part, off);
    if (lane == 0)
        atomAddF(&pred[rid[g]], (part + b2[0]) * rsign[g]);
}

extern "C" void kernel_launch(void* const* d_in, const int* in_sizes, int n_in,
                              void* d_out, int out_size, void* d_ws, size_t ws_size,
                              hipStream_t stream) {
    const float* h0      = (const float*)d_in[0];
    const float* pos     = (const float*)d_in[1];
    const int*   edges   = (const int*)d_in[2];
    const float* nmask   = (const float*)d_in[3];
    const float* emask   = (const float*)d_in[4];
    const int*   rid     = (const int*)d_in[5];
    const float* rsign   = (const float*)d_in[6];
    const float* emb_w   = (const float*)d_in[7];
    const float* emb_b   = (const float*)d_in[8];
    const float* edge_w1 = (const float*)d_in[9];
    const float* edge_b1 = (const float*)d_in[10];
    const float* edge_w2 = (const float*)d_in[11];
    const float* edge_b2 = (const float*)d_in[12];
    const float* node_w1 = (const float*)d_in[13];
    const float* node_b1 = (const float*)d_in[14];
    const float* node_w2 = (const float*)d_in[15];
    const float* node_b2 = (const float*)d_in[16];
    const float* dec_w1  = (const float*)d_in[17];
    const float* dec_b1  = (const float*)d_in[18];
    const float* dec_w2  = (const float*)d_in[19];
    const float* dec_b2  = (const float*)d_in[20];
    const float* g_w1    = (const float*)d_in[21];
    const float* g_b1    = (const float*)d_in[22];
    const float* g_w2    = (const float*)d_in[23];
    const float* g_b2    = (const float*)d_in[24];

    float* h      = (float*)d_ws;            // N*H
    float* agg    = h + N_NODES * H;         // N*H
    float* radial = agg + N_NODES * H;       // E
    float* PA     = radial + N_EDGES;        // N*H
    float* PB     = PA + N_NODES * H;        // N*H
    float* pred   = (float*)d_out;

    hipMemsetAsync(d_out, 0, R_REACT * sizeof(float), stream);
    k_embed<<<(N_NODES * H) / 256, 256, 0, stream>>>(h0, emb_w, emb_b, h, agg);
    k_radial<<<N_EDGES / 256, 256, 0, stream>>>(edges, pos, radial);

    for (int i = 0; i < L_LAYERS; ++i) {
        k_nodeproj<<<N_NODES / NPB, 64, 0, stream>>>(
            h, edge_w1 + i * EIN * H, edge_b1 + i * H, PA, PB);
        k_edge2<<<N_EDGES / EPB2, 64, 0, stream>>>(
            PA, PB, radial, edges, emask,
            edge_w1 + i * EIN * H,
            edge_w2 + i * H * H, edge_b2 + i * H, agg);
        k_node<<<N_NODES / NPB, 64, 0, stream>>>(
            h, agg, h0,
            node_w1 + i * NIN * H, node_b1 + i * H,
            node_w2 + i * H * H,   node_b2 + i * H);
    }
    k_dec<<<N_NODES / NPB, 64, 0, stream>>>(h, nmask, dec_w1, dec_b1, dec_w2, dec_b2);
    k_graph<<<G_GRAPHS, 64, 0, stream>>>(h, rid, rsign, g_w1, g_b1, g_w2, g_b2, pred);
}

// Round 3
// 760.460 us; speedup vs baseline: 1.8221x; 1.0085x over previous
//
#include <hip/hip_runtime.h>
#include <math.h>

#define N_NODES 32768
#define N_EDGES 491520
#define F_IN    11
#define H       64
#define G_GRAPHS 2048
#define NN_PER_G 16
#define R_REACT 1024
#define L_LAYERS 4
#define EIN     129   // 2H+1
#define NIN     139   // 2H+F
#define NPB     16    // nodes per block
#define TPB_E   8     // 16-edge tiles per block in k_edge3 (128 edges/block)

typedef __attribute__((ext_vector_type(8))) short short8;
typedef __attribute__((ext_vector_type(4))) float f32x4;

__device__ __forceinline__ float silu_f(float x) {
    return x / (1.0f + __expf(-x));
}

__device__ __forceinline__ void atomAddF(float* p, float v) {
    unsafeAtomicAdd(p, v);   // global_atomic_add_f32
}

__device__ __forceinline__ unsigned short f2bf(float x) {   // RNE
    union { float f; unsigned u; } v; v.f = x;
    unsigned r = v.u + 0x7FFFu + ((v.u >> 16) & 1u);
    return (unsigned short)(r >> 16);
}
__device__ __forceinline__ float bf2f(unsigned short b) {
    union { float f; unsigned u; } v; v.u = ((unsigned)b) << 16;
    return v.f;
}

// ---------------- embed: h = h0 @ emb_w + emb_b ; agg = 0 ----------------
__global__ __launch_bounds__(256) void k_embed(
        const float* __restrict__ h0, const float* __restrict__ emb_w,
        const float* __restrict__ emb_b,
        float* __restrict__ h, float* __restrict__ agg) {
    int tid = blockIdx.x * 256 + threadIdx.x;   // N*H threads
    int n = tid >> 6, j = tid & 63;
    float acc = emb_b[j];
#pragma unroll
    for (int k = 0; k < F_IN; ++k)
        acc += h0[n * F_IN + k] * emb_w[k * H + j];
    h[tid] = acc;
    agg[tid] = 0.0f;
}

// ---------------- radial per edge ----------------
__global__ __launch_bounds__(256) void k_radial(
        const int* __restrict__ edges, const float* __restrict__ pos,
        float* __restrict__ radial) {
    int e = blockIdx.x * 256 + threadIdx.x;
    if (e < N_EDGES) {
        int r = edges[e], c = edges[N_EDGES + e];
        float dx = pos[r * 3 + 0] - pos[c * 3 + 0];
        float dy = pos[r * 3 + 1] - pos[c * 3 + 1];
        float dz = pos[r * 3 + 2] - pos[c * 3 + 2];
        radial[e] = dx * dx + dy * dy + dz * dz;
    }
}

// ---------------- node projection: PA = h@W1a + b1 ; PB = h@W1b ----------
__global__ __launch_bounds__(64, 2) void k_nodeproj(
        const float* __restrict__ h,
        const float* __restrict__ W1,   // [EIN x H] for this layer
        const float* __restrict__ b1,
        float* __restrict__ PA, float* __restrict__ PB) {
    const int lane = threadIdx.x;
    float w1a[H], w1b[H];
#pragma unroll
    for (int k = 0; k < H; ++k) w1a[k] = W1[k * H + lane];
#pragma unroll
    for (int k = 0; k < H; ++k) w1b[k] = W1[(H + k) * H + lane];
    const float bias1 = b1[lane];

    __shared__ __align__(16) float xb[2][64];

    const int base = blockIdx.x * NPB;
    for (int p = 0; p < NPB; p += 2) {
        const int n0 = base + p, n1 = n0 + 1;
        __syncthreads();
        xb[0][lane] = h[n0 * H + lane];
        xb[1][lane] = h[n1 * H + lane];
        __syncthreads();

        float pa0 = bias1, pb0 = 0.0f, pa1 = bias1, pb1 = 0.0f;
        const float4* x0 = (const float4*)(&xb[0][0]);
        const float4* x1 = (const float4*)(&xb[1][0]);
#pragma unroll
        for (int m = 0; m < 16; ++m) {
            float4 v0 = x0[m], v1 = x1[m];
            pa0 += v0.x * w1a[4 * m + 0]; pb0 += v0.x * w1b[4 * m + 0];
            pa1 += v1.x * w1a[4 * m + 0]; pb1 += v1.x * w1b[4 * m + 0];
            pa0 += v0.y * w1a[4 * m + 1]; pb0 += v0.y * w1b[4 * m + 1];
            pa1 += v1.y * w1a[4 * m + 1]; pb1 += v1.y * w1b[4 * m + 1];
            pa0 += v0.z * w1a[4 * m + 2]; pb0 += v0.z * w1b[4 * m + 2];
            pa1 += v1.z * w1a[4 * m + 2]; pb1 += v1.z * w1b[4 * m + 2];
            pa0 += v0.w * w1a[4 * m + 3]; pb0 += v0.w * w1b[4 * m + 3];
            pa1 += v1.w * w1a[4 * m + 3]; pb1 += v1.w * w1b[4 * m + 3];
        }
        PA[n0 * H + lane] = pa0;
        PB[n0 * H + lane] = pb0;
        PA[n1 * H + lane] = pa1;
        PB[n1 * H + lane] = pb1;
    }
}

// ---------------- edge via MFMA (split-bf16 ~= fp32 accuracy) ------------
// Per 16-edge tile: lane gathers its 8+8 k-values of silu(PA[r]+PB[c]+rad*w1c)
// straight from global (no LDS), GEMM2 = 24 mfma_f32_16x16x32_bf16, scatter.
__global__ __launch_bounds__(64, 2) void k_edge3(
        const float* __restrict__ PA, const float* __restrict__ PB,
        const float* __restrict__ radial,
        const int* __restrict__ edges, const float* __restrict__ emask,
        const float* __restrict__ W1,   // only row 128 (w1c) used
        const float* __restrict__ W2, const float* __restrict__ b2,
        float* __restrict__ agg) {
    const int lane = threadIdx.x;
    const int quad = lane >> 4;
    const int m16  = lane & 15;

    // one-time: W2 -> bf16 hi/lo B fragments, register-stationary.
    // B[k][n]: k = kf*32 + quad*8 + j, n = nt*16 + m16
    short8 Bh[8], Bl[8];             // index [nt*2+kf]
#pragma unroll
    for (int nt = 0; nt < 4; ++nt) {
#pragma unroll
        for (int kf = 0; kf < 2; ++kf) {
            short8 bh, bl;
#pragma unroll
            for (int j = 0; j < 8; ++j) {
                float w = W2[(kf * 32 + quad * 8 + j) * H + nt * 16 + m16];
                unsigned short hi = f2bf(w);
                bh[j] = (short)hi;
                bl[j] = (short)f2bf(w - bf2f(hi));
            }
            Bh[nt * 2 + kf] = bh; Bl[nt * 2 + kf] = bl;
        }
    }
    float w1cr[16];
#pragma unroll
    for (int i = 0; i < 16; ++i) {
        int k = (i < 8) ? (quad * 8 + i) : (32 + quad * 8 + (i - 8));
        w1cr[i] = W1[128 * H + k];
    }
    float b2v[4];
#pragma unroll
    for (int nt = 0; nt < 4; ++nt) b2v[nt] = b2[nt * 16 + m16];

    for (int t = 0; t < TPB_E; ++t) {
        const int base = (blockIdx.x * TPB_E + t) * 16;
        const int e = base + m16;          // this lane's A-row edge
        const int r = edges[e], c = edges[N_EDGES + e];
        const float rad = radial[e];

        const float* par = PA + r * H + quad * 8;
        const float* pbr = PB + c * H + quad * 8;
        float av[16], bv[16];
        *(float4*)&av[0]  = *(const float4*)(par + 0);
        *(float4*)&av[4]  = *(const float4*)(par + 4);
        *(float4*)&av[8]  = *(const float4*)(par + 32);
        *(float4*)&av[12] = *(const float4*)(par + 36);
        *(float4*)&bv[0]  = *(const float4*)(pbr + 0);
        *(float4*)&bv[4]  = *(const float4*)(pbr + 4);
        *(float4*)&bv[8]  = *(const float4*)(pbr + 32);
        *(float4*)&bv[12] = *(const float4*)(pbr + 36);

        unsigned short sh[16], sl[16];
#pragma unroll
        for (int i = 0; i < 16; ++i) {
            float tt = av[i] + bv[i] + rad * w1cr[i];
            float sv = silu_f(tt);
            unsigned short hi = f2bf(sv);
            sh[i] = hi;
            sl[i] = f2bf(sv - bf2f(hi));
        }
        short8 Ah0, Ah1, Al0, Al1;
#pragma unroll
        for (int j = 0; j < 8; ++j) {
            Ah0[j] = (short)sh[j];     Ah1[j] = (short)sh[8 + j];
            Al0[j] = (short)sl[j];     Al1[j] = (short)sl[8 + j];
        }

        f32x4 acc[4];
#pragma unroll
        for (int nt = 0; nt < 4; ++nt) {
            f32x4 a = {0.0f, 0.0f, 0.0f, 0.0f};
            a = __builtin_amdgcn_mfma_f32_16x16x32_bf16(Ah0, Bh[nt*2+0], a, 0, 0, 0);
            a = __builtin_amdgcn_mfma_f32_16x16x32_bf16(Ah1, Bh[nt*2+1], a, 0, 0, 0);
            a = __builtin_amdgcn_mfma_f32_16x16x32_bf16(Ah0, Bl[nt*2+0], a, 0, 0, 0);
            a = __builtin_amdgcn_mfma_f32_16x16x32_bf16(Ah1, Bl[nt*2+1], a, 0, 0, 0);
            a = __builtin_amdgcn_mfma_f32_16x16x32_bf16(Al0, Bh[nt*2+0], a, 0, 0, 0);
            a = __builtin_amdgcn_mfma_f32_16x16x32_bf16(Al1, Bh[nt*2+1], a, 0, 0, 0);
            acc[nt] = a;
        }

        // D layout: row(edge) = quad*4 + reg, col = nt*16 + m16
#pragma unroll
        for (int r4 = 0; r4 < 4; ++r4) {
            const int em = base + quad * 4 + r4;
            const int rowm = edges[em];
            const float msk = emask[em];
            float* aggp = agg + rowm * H + m16;
#pragma unroll
            for (int nt = 0; nt < 4; ++nt) {
                float o = acc[nt][r4] + b2v[nt];
                o = silu_f(o) * msk;
                atomAddF(aggp + nt * 16, o);
            }
        }
    }
}

// ---------------- node MLP: h = silu([h,agg,h0]@W1+b1)@W2+b2 ; agg=0 -----
__global__ __launch_bounds__(64, 2) void k_node(
        float* __restrict__ h, float* __restrict__ agg,
        const float* __restrict__ h0,
        const float* __restrict__ W1, const float* __restrict__ b1,
        const float* __restrict__ W2, const float* __restrict__ b2) {
    const int lane = threadIdx.x;

    float w1r[NIN];
#pragma unroll
    for (int k = 0; k < NIN; ++k) w1r[k] = W1[k * H + lane];
    float w2r[H];
#pragma unroll
    for (int k = 0; k < H; ++k) w2r[k] = W2[k * H + lane];
    const float bias1 = b1[lane], bias2 = b2[lane];

    __shared__ __align__(16) float xb[2][140];  // [h | agg | h0]
    __shared__ __align__(16) float tb[2][64];

    const int base = blockIdx.x * NPB;
    for (int p = 0; p < NPB; p += 2) {
        const int n0 = base + p, n1 = n0 + 1;
        xb[0][lane]      = h[n0 * H + lane];
        xb[0][64 + lane] = agg[n0 * H + lane];
        xb[1][lane]      = h[n1 * H + lane];
        xb[1][64 + lane] = agg[n1 * H + lane];
        if (lane < F_IN) {
            xb[0][128 + lane] = h0[n0 * F_IN + lane];
            xb[1][128 + lane] = h0[n1 * F_IN + lane];
        }
        agg[n0 * H + lane] = 0.0f;   // ready for next layer's edge kernel
        agg[n1 * H + lane] = 0.0f;
        __syncthreads();

        float a0 = bias1, a1 = bias1;
        const float4* x0 = (const float4*)(&xb[0][0]);
        const float4* x1 = (const float4*)(&xb[1][0]);
#pragma unroll
        for (int m = 0; m < 34; ++m) {   // 136 of 139
            float4 v0 = x0[m], v1 = x1[m];
            a0 += v0.x * w1r[4 * m + 0]; a1 += v1.x * w1r[4 * m + 0];
            a0 += v0.y * w1r[4 * m + 1]; a1 += v1.y * w1r[4 * m + 1];
            a0 += v0.z * w1r[4 * m + 2]; a1 += v1.z * w1r[4 * m + 2];
            a0 += v0.w * w1r[4 * m + 3]; a1 += v1.w * w1r[4 * m + 3];
        }
#pragma unroll
        for (int k = 136; k < NIN; ++k) {
            a0 += xb[0][k] * w1r[k];
            a1 += xb[1][k] * w1r[k];
        }
        float s0 = silu_f(a0), s1 = silu_f(a1);
        __syncthreads();
        tb[0][lane] = s0; tb[1][lane] = s1;
        __syncthreads();

        float o0 = bias2, o1 = bias2;
        const float4* q0 = (const float4*)(&tb[0][0]);
        const float4* q1 = (const float4*)(&tb[1][0]);
#pragma unroll
        for (int m = 0; m < 16; ++m) {
            float4 v0 = q0[m], v1 = q1[m];
            o0 += v0.x * w2r[4 * m + 0]; o1 += v1.x * w2r[4 * m + 0];
            o0 += v0.y * w2r[4 * m + 1]; o1 += v1.y * w2r[4 * m + 1];
            o0 += v0.z * w2r[4 * m + 2]; o1 += v1.z * w2r[4 * m + 2];
            o0 += v0.w * w2r[4 * m + 3]; o1 += v1.w * w2r[4 * m + 3];
        }
        h[n0 * H + lane] = o0;   // no trailing silu in node model
        h[n1 * H + lane] = o1;
        __syncthreads();
    }
}

// ---------------- node decoder: h = (silu(h@W1+b1)@W2+b2) * node_mask ----
__global__ __launch_bounds__(64, 4) void k_dec(
        float* __restrict__ h, const float* __restrict__ nmask,
        const float* __restrict__ W1, const float* __restrict__ b1,
        const float* __restrict__ W2, const float* __restrict__ b2) {
    const int lane = threadIdx.x;
    float w1r[H], w2r[H];
#pragma unroll
    for (int k = 0; k < H; ++k) w1r[k] = W1[k * H + lane];
#pragma unroll
    for (int k = 0; k < H; ++k) w2r[k] = W2[k * H + lane];
    const float bias1 = b1[lane], bias2 = b2[lane];

    __shared__ __align__(16) float xb[2][64];
    __shared__ __align__(16) float tb[2][64];

    const int base = blockIdx.x * NPB;
    for (int p = 0; p < NPB; p += 2) {
        const int n0 = base + p, n1 = n0 + 1;
        xb[0][lane] = h[n0 * H + lane];
        xb[1][lane] = h[n1 * H + lane];
        __syncthreads();
        float a0 = bias1, a1 = bias1;
        const float4* x0 = (const float4*)(&xb[0][0]);
        const float4* x1 = (const float4*)(&xb[1][0]);
#pragma unroll
        for (int m = 0; m < 16; ++m) {
            float4 v0 = x0[m], v1 = x1[m];
            a0 += v0.x * w1r[4 * m + 0]; a1 += v1.x * w1r[4 * m + 0];
            a0 += v0.y * w1r[4 * m + 1]; a1 += v1.y * w1r[4 * m + 1];
            a0 += v0.z * w1r[4 * m + 2]; a1 += v1.z * w1r[4 * m + 2];
            a0 += v0.w * w1r[4 * m + 3]; a1 += v1.w * w1r[4 * m + 3];
        }
        float s0 = silu_f(a0), s1 = silu_f(a1);
        __syncthreads();
        tb[0][lane] = s0; tb[1][lane] = s1;
        __syncthreads();
        float o0 = bias2, o1 = bias2;
        const float4* q0 = (const float4*)(&tb[0][0]);
        const float4* q1 = (const float4*)(&tb[1][0]);
#pragma unroll
        for (int m = 0; m < 16; ++m) {
            float4 v0 = q0[m], v1 = q1[m];
            o0 += v0.x * w2r[4 * m + 0]; o1 += v1.x * w2r[4 * m + 0];
            o0 += v0.y * w2r[4 * m + 1]; o1 += v1.y * w2r[4 * m + 1];
            o0 += v0.z * w2r[4 * m + 2]; o1 += v1.z * w2r[4 * m + 2];
            o0 += v0.w * w2r[4 * m + 3]; o1 += v1.w * w2r[4 * m + 3];
        }
        h[n0 * H + lane] = o0 * nmask[n0];
        h[n1 * H + lane] = o1 * nmask[n1];
        __syncthreads();
    }
}

// ---------------- pool + graph decoder + signed reaction aggregation -----
__global__ __launch_bounds__(64) void k_graph(
        const float* __restrict__ h, const int* __restrict__ rid,
        const float* __restrict__ rsign,
        const float* __restrict__ W1, const float* __restrict__ b1,
        const float* __restrict__ W2, const float* __restrict__ b2,
        float* __restrict__ pred) {
    const int g = blockIdx.x;
    const int lane = threadIdx.x;
    float hgv = 0.0f;
#pragma unroll
    for (int m = 0; m < NN_PER_G; ++m)
        hgv += h[(g * NN_PER_G + m) * H + lane];
    __shared__ __align__(16) float hgs[64];
    hgs[lane] = hgv;
    __syncthreads();
    float acc = b1[lane];
#pragma unroll
    for (int k = 0; k < H; ++k)
        acc += hgs[k] * W1[k * H + lane];
    float part = silu_f(acc) * W2[lane];
#pragma unroll
    for (int off = 32; off > 0; off >>= 1)
        part += __shfl_down(part, off);
    if (lane == 0)
        atomAddF(&pred[rid[g]], (part + b2[0]) * rsign[g]);
}

extern "C" void kernel_launch(void* const* d_in, const int* in_sizes, int n_in,
                              void* d_out, int out_size, void* d_ws, size_t ws_size,
                              hipStream_t stream) {
    const float* h0      = (const float*)d_in[0];
    const float* pos     = (const float*)d_in[1];
    const int*   edges   = (const int*)d_in[2];
    const float* nmask   = (const float*)d_in[3];
    const float* emask   = (const float*)d_in[4];
    const int*   rid     = (const int*)d_in[5];
    const float* rsign   = (const float*)d_in[6];
    const float* emb_w   = (const float*)d_in[7];
    const float* emb_b   = (const float*)d_in[8];
    const float* edge_w1 = (const float*)d_in[9];
    const float* edge_b1 = (const float*)d_in[10];
    const float* edge_w2 = (const float*)d_in[11];
    const float* edge_b2 = (const float*)d_in[12];
    const float* node_w1 = (const float*)d_in[13];
    const float* node_b1 = (const float*)d_in[14];
    const float* node_w2 = (const float*)d_in[15];
    const float* node_b2 = (const float*)d_in[16];
    const float* dec_w1  = (const float*)d_in[17];
    const float* dec_b1  = (const float*)d_in[18];
    const float* dec_w2  = (const float*)d_in[19];
    const float* dec_b2  = (const float*)d_in[20];
    const float* g_w1    = (const float*)d_in[21];
    const float* g_b1    = (const float*)d_in[22];
    const float* g_w2    = (const float*)d_in[23];
    const float* g_b2    = (const float*)d_in[24];

    float* h      = (float*)d_ws;            // N*H
    float* agg    = h + N_NODES * H;         // N*H
    float* radial = agg + N_NODES * H;       // E
    float* PA     = radial + N_EDGES;        // N*H
    float* PB     = PA + N_NODES * H;        // N*H
    float* pred   = (float*)d_out;

    hipMemsetAsync(d_out, 0, R_REACT * sizeof(float), stream);
    k_embed<<<(N_NODES * H) / 256, 256, 0, stream>>>(h0, emb_w, emb_b, h, agg);
    k_radial<<<N_EDGES / 256, 256, 0, stream>>>(edges, pos, radial);

    for (int i = 0; i < L_LAYERS; ++i) {
        k_nodeproj<<<N_NODES / NPB, 64, 0, stream>>>(
            h, edge_w1 + i * EIN * H, edge_b1 + i * H, PA, PB);
        k_edge3<<<N_EDGES / (16 * TPB_E), 64, 0, stream>>>(
            PA, PB, radial, edges, emask,
            edge_w1 + i * EIN * H,
            edge_w2 + i * H * H, edge_b2 + i * H, agg);
        k_node<<<N_NODES / NPB, 64, 0, stream>>>(
            h, agg, h0,
            node_w1 + i * NIN * H, node_b1 + i * H,
            node_w2 + i * H * H,   node_b2 + i * H);
    }
    k_dec<<<N_NODES / NPB, 64, 0, stream>>>(h, nmask, dec_w1, dec_b1, dec_w2, dec_b2);
    k_graph<<<G_GRAPHS, 64, 0, stream>>>(h, rid, rsign, g_w1, g_b1, g_w2, g_b2, pred);
}

// Round 4
// 749.395 us; speedup vs baseline: 1.8490x; 1.0148x over previous
//
#include <hip/hip_runtime.h>
#include <math.h>

#define N_NODES 32768
#define N_EDGES 491520
#define F_IN    11
#define H       64
#define G_GRAPHS 2048
#define NN_PER_G 16
#define R_REACT 1024
#define L_LAYERS 4
#define EIN     129   // 2H+1
#define NIN     139   // 2H+F
#define NPB     16    // nodes per block
#define TPW     8     // 16-edge tiles per wave in k_edge4

typedef __attribute__((ext_vector_type(8))) short short8;
typedef __attribute__((ext_vector_type(4))) float f32x4;

__device__ __forceinline__ float silu_f(float x) {
    return x / (1.0f + __expf(-x));
}

__device__ __forceinline__ void atomAddF(float* p, float v) {
    unsafeAtomicAdd(p, v);   // global_atomic_add_f32
}

__device__ __forceinline__ float bf2f(unsigned short b) {
    union { float f; unsigned u; } v; v.u = ((unsigned)b) << 16;
    return v.f;
}
// truncation split: hi = top 16 bits, lo = trunc16(x - hi). |err| ~ 2^-15 rel.
__device__ __forceinline__ void splitbf(float x, unsigned short& hi, unsigned short& lo) {
    union { float f; unsigned u; } v; v.f = x;
    hi = (unsigned short)(v.u >> 16);
    union { float f; unsigned u; } w; w.f = x - bf2f(hi);
    lo = (unsigned short)(w.u >> 16);
}

// ---------------- embed: h = h0 @ emb_w + emb_b ; agg = 0 ----------------
__global__ __launch_bounds__(256) void k_embed(
        const float* __restrict__ h0, const float* __restrict__ emb_w,
        const float* __restrict__ emb_b,
        float* __restrict__ h, float* __restrict__ agg) {
    int tid = blockIdx.x * 256 + threadIdx.x;   // N*H threads
    int n = tid >> 6, j = tid & 63;
    float acc = emb_b[j];
#pragma unroll
    for (int k = 0; k < F_IN; ++k)
        acc += h0[n * F_IN + k] * emb_w[k * H + j];
    h[tid] = acc;
    agg[tid] = 0.0f;
}

// ---------------- radial per edge ----------------
__global__ __launch_bounds__(256) void k_radial(
        const int* __restrict__ edges, const float* __restrict__ pos,
        float* __restrict__ radial) {
    int e = blockIdx.x * 256 + threadIdx.x;
    if (e < N_EDGES) {
        int r = edges[e], c = edges[N_EDGES + e];
        float dx = pos[r * 3 + 0] - pos[c * 3 + 0];
        float dy = pos[r * 3 + 1] - pos[c * 3 + 1];
        float dz = pos[r * 3 + 2] - pos[c * 3 + 2];
        radial[e] = dx * dx + dy * dy + dz * dz;
    }
}

// ---------------- node projection: PA = h@W1a + b1 ; PB = h@W1b ----------
__global__ __launch_bounds__(64, 2) void k_nodeproj(
        const float* __restrict__ h,
        const float* __restrict__ W1,   // [EIN x H] for this layer
        const float* __restrict__ b1,
        float* __restrict__ PA, float* __restrict__ PB) {
    const int lane = threadIdx.x;
    float w1a[H], w1b[H];
#pragma unroll
    for (int k = 0; k < H; ++k) w1a[k] = W1[k * H + lane];
#pragma unroll
    for (int k = 0; k < H; ++k) w1b[k] = W1[(H + k) * H + lane];
    const float bias1 = b1[lane];

    __shared__ __align__(16) float xb[2][64];

    const int base = blockIdx.x * NPB;
    for (int p = 0; p < NPB; p += 2) {
        const int n0 = base + p, n1 = n0 + 1;
        __syncthreads();
        xb[0][lane] = h[n0 * H + lane];
        xb[1][lane] = h[n1 * H + lane];
        __syncthreads();

        float pa0 = bias1, pb0 = 0.0f, pa1 = bias1, pb1 = 0.0f;
        const float4* x0 = (const float4*)(&xb[0][0]);
        const float4* x1 = (const float4*)(&xb[1][0]);
#pragma unroll
        for (int m = 0; m < 16; ++m) {
            float4 v0 = x0[m], v1 = x1[m];
            pa0 += v0.x * w1a[4 * m + 0]; pb0 += v0.x * w1b[4 * m + 0];
            pa1 += v1.x * w1a[4 * m + 0]; pb1 += v1.x * w1b[4 * m + 0];
            pa0 += v0.y * w1a[4 * m + 1]; pb0 += v0.y * w1b[4 * m + 1];
            pa1 += v1.y * w1a[4 * m + 1]; pb1 += v1.y * w1b[4 * m + 1];
            pa0 += v0.z * w1a[4 * m + 2]; pb0 += v0.z * w1b[4 * m + 2];
            pa1 += v1.z * w1a[4 * m + 2]; pb1 += v1.z * w1b[4 * m + 2];
            pa0 += v0.w * w1a[4 * m + 3]; pb0 += v0.w * w1b[4 * m + 3];
            pa1 += v1.w * w1a[4 * m + 3]; pb1 += v1.w * w1b[4 * m + 3];
        }
        PA[n0 * H + lane] = pa0;
        PB[n0 * H + lane] = pb0;
        PA[n1 * H + lane] = pa1;
        PB[n1 * H + lane] = pb1;
    }
}

// ---------------- edge via MFMA, 4 waves/block, 2-deep pipeline ----------
__global__ __launch_bounds__(256, 2) void k_edge4(
        const float* __restrict__ PA, const float* __restrict__ PB,
        const float* __restrict__ radial,
        const int* __restrict__ edges, const float* __restrict__ emask,
        const float* __restrict__ W1,   // only row 128 (w1c) used
        const float* __restrict__ W2, const float* __restrict__ b2,
        float* __restrict__ agg) {
    const int lane = threadIdx.x & 63;
    const int wave = threadIdx.x >> 6;
    const int quad = lane >> 4;
    const int m16  = lane & 15;

    // one-time: W2 -> bf16 hi/lo B fragments, register-stationary.
    short8 Bh[8], Bl[8];             // index [nt*2+kf]
#pragma unroll
    for (int nt = 0; nt < 4; ++nt) {
#pragma unroll
        for (int kf = 0; kf < 2; ++kf) {
            short8 bh, bl;
#pragma unroll
            for (int j = 0; j < 8; ++j) {
                float w = W2[(kf * 32 + quad * 8 + j) * H + nt * 16 + m16];
                unsigned short hi, lo;
                splitbf(w, hi, lo);
                bh[j] = (short)hi;
                bl[j] = (short)lo;
            }
            Bh[nt * 2 + kf] = bh; Bl[nt * 2 + kf] = bl;
        }
    }
    float w1cr[16];
#pragma unroll
    for (int i = 0; i < 16; ++i) {
        int k = (i < 8) ? (quad * 8 + i) : (32 + quad * 8 + (i - 8));
        w1cr[i] = W1[128 * H + k];
    }
    float b2v[4];
#pragma unroll
    for (int nt = 0; nt < 4; ++nt) b2v[nt] = b2[nt * 16 + m16];

    const int tile0 = (blockIdx.x * 4 + wave) * TPW;

    // ---- prologue: tile 0 loads ----
    int eA = tile0 * 16 + m16;
    int rA = edges[eA], cA = edges[N_EDGES + eA];
    float radA = radial[eA], mskA = emask[eA];
    float avA[16], bvA[16];
    {
        const float* par = PA + rA * H + quad * 8;
        const float* pbr = PB + cA * H + quad * 8;
        *(float4*)&avA[0]  = *(const float4*)(par + 0);
        *(float4*)&avA[4]  = *(const float4*)(par + 4);
        *(float4*)&avA[8]  = *(const float4*)(par + 32);
        *(float4*)&avA[12] = *(const float4*)(par + 36);
        *(float4*)&bvA[0]  = *(const float4*)(pbr + 0);
        *(float4*)&bvA[4]  = *(const float4*)(pbr + 4);
        *(float4*)&bvA[8]  = *(const float4*)(pbr + 32);
        *(float4*)&bvA[12] = *(const float4*)(pbr + 36);
    }

#pragma unroll 2
    for (int t = 0; t < TPW; ++t) {
        // ---- prefetch tile t+1 while computing tile t ----
        int rB = 0, cB = 0;
        float radB = 0.0f, mskB = 0.0f;
        float avB[16], bvB[16];
        if (t + 1 < TPW) {
            const int eB = (tile0 + t + 1) * 16 + m16;
            rB = edges[eB]; cB = edges[N_EDGES + eB];
            radB = radial[eB]; mskB = emask[eB];
            const float* par = PA + rB * H + quad * 8;
            const float* pbr = PB + cB * H + quad * 8;
            *(float4*)&avB[0]  = *(const float4*)(par + 0);
            *(float4*)&avB[4]  = *(const float4*)(par + 4);
            *(float4*)&avB[8]  = *(const float4*)(par + 32);
            *(float4*)&avB[12] = *(const float4*)(par + 36);
            *(float4*)&bvB[0]  = *(const float4*)(pbr + 0);
            *(float4*)&bvB[4]  = *(const float4*)(pbr + 4);
            *(float4*)&bvB[8]  = *(const float4*)(pbr + 32);
            *(float4*)&bvB[12] = *(const float4*)(pbr + 36);
        }

        // ---- compute tile t ----
        unsigned short sh[16], sl[16];
#pragma unroll
        for (int i = 0; i < 16; ++i) {
            float tt = avA[i] + bvA[i] + radA * w1cr[i];
            float sv = silu_f(tt);
            splitbf(sv, sh[i], sl[i]);
        }
        short8 Ah0, Ah1, Al0, Al1;
#pragma unroll
        for (int j = 0; j < 8; ++j) {
            Ah0[j] = (short)sh[j];     Ah1[j] = (short)sh[8 + j];
            Al0[j] = (short)sl[j];     Al1[j] = (short)sl[8 + j];
        }

        f32x4 acc[4];
#pragma unroll
        for (int nt = 0; nt < 4; ++nt) {
            f32x4 a = {0.0f, 0.0f, 0.0f, 0.0f};
            a = __builtin_amdgcn_mfma_f32_16x16x32_bf16(Ah0, Bh[nt*2+0], a, 0, 0, 0);
            a = __builtin_amdgcn_mfma_f32_16x16x32_bf16(Ah1, Bh[nt*2+1], a, 0, 0, 0);
            a = __builtin_amdgcn_mfma_f32_16x16x32_bf16(Ah0, Bl[nt*2+0], a, 0, 0, 0);
            a = __builtin_amdgcn_mfma_f32_16x16x32_bf16(Ah1, Bl[nt*2+1], a, 0, 0, 0);
            a = __builtin_amdgcn_mfma_f32_16x16x32_bf16(Al0, Bh[nt*2+0], a, 0, 0, 0);
            a = __builtin_amdgcn_mfma_f32_16x16x32_bf16(Al1, Bh[nt*2+1], a, 0, 0, 0);
            acc[nt] = a;
        }

        // ---- epilogue: D row(edge) = quad*4 + r4, col = nt*16 + m16 ----
        // row index & mask come from lanes 0..15 of this wave via shfl.
#pragma unroll
        for (int r4 = 0; r4 < 4; ++r4) {
            const int rowm  = __shfl(rA, quad * 4 + r4);
            const float msk = __shfl(mskA, quad * 4 + r4);
            float* aggp = agg + rowm * H + m16;
#pragma unroll
            for (int nt = 0; nt < 4; ++nt) {
                float o = acc[nt][r4] + b2v[nt];
                o = silu_f(o) * msk;
                atomAddF(aggp + nt * 16, o);
            }
        }

        // ---- rotate pipeline regs ----
        if (t + 1 < TPW) {
            rA = rB; cA = cB; radA = radB; mskA = mskB;
#pragma unroll
            for (int i = 0; i < 16; ++i) { avA[i] = avB[i]; bvA[i] = bvB[i]; }
        }
    }
}

// ---------------- node MLP: h = silu([h,agg,h0]@W1+b1)@W2+b2 ; agg=0 -----
__global__ __launch_bounds__(64, 2) void k_node(
        float* __restrict__ h, float* __restrict__ agg,
        const float* __restrict__ h0,
        const float* __restrict__ W1, const float* __restrict__ b1,
        const float* __restrict__ W2, const float* __restrict__ b2) {
    const int lane = threadIdx.x;

    float w1r[NIN];
#pragma unroll
    for (int k = 0; k < NIN; ++k) w1r[k] = W1[k * H + lane];
    float w2r[H];
#pragma unroll
    for (int k = 0; k < H; ++k) w2r[k] = W2[k * H + lane];
    const float bias1 = b1[lane], bias2 = b2[lane];

    __shared__ __align__(16) float xb[2][140];  // [h | agg | h0]
    __shared__ __align__(16) float tb[2][64];

    const int base = blockIdx.x * NPB;
    for (int p = 0; p < NPB; p += 2) {
        const int n0 = base + p, n1 = n0 + 1;
        xb[0][lane]      = h[n0 * H + lane];
        xb[0][64 + lane] = agg[n0 * H + lane];
        xb[1][lane]      = h[n1 * H + lane];
        xb[1][64 + lane] = agg[n1 * H + lane];
        if (lane < F_IN) {
            xb[0][128 + lane] = h0[n0 * F_IN + lane];
            xb[1][128 + lane] = h0[n1 * F_IN + lane];
        }
        agg[n0 * H + lane] = 0.0f;   // ready for next layer's edge kernel
        agg[n1 * H + lane] = 0.0f;
        __syncthreads();

        float a0 = bias1, a1 = bias1;
        const float4* x0 = (const float4*)(&xb[0][0]);
        const float4* x1 = (const float4*)(&xb[1][0]);
#pragma unroll
        for (int m = 0; m < 34; ++m) {   // 136 of 139
            float4 v0 = x0[m], v1 = x1[m];
            a0 += v0.x * w1r[4 * m + 0]; a1 += v1.x * w1r[4 * m + 0];
            a0 += v0.y * w1r[4 * m + 1]; a1 += v1.y * w1r[4 * m + 1];
            a0 += v0.z * w1r[4 * m + 2]; a1 += v1.z * w1r[4 * m + 2];
            a0 += v0.w * w1r[4 * m + 3]; a1 += v1.w * w1r[4 * m + 3];
        }
#pragma unroll
        for (int k = 136; k < NIN; ++k) {
            a0 += xb[0][k] * w1r[k];
            a1 += xb[1][k] * w1r[k];
        }
        float s0 = silu_f(a0), s1 = silu_f(a1);
        __syncthreads();
        tb[0][lane] = s0; tb[1][lane] = s1;
        __syncthreads();

        float o0 = bias2, o1 = bias2;
        const float4* q0 = (const float4*)(&tb[0][0]);
        const float4* q1 = (const float4*)(&tb[1][0]);
#pragma unroll
        for (int m = 0; m < 16; ++m) {
            float4 v0 = q0[m], v1 = q1[m];
            o0 += v0.x * w2r[4 * m + 0]; o1 += v1.x * w2r[4 * m + 0];
            o0 += v0.y * w2r[4 * m + 1]; o1 += v1.y * w2r[4 * m + 1];
            o0 += v0.z * w2r[4 * m + 2]; o1 += v1.z * w2r[4 * m + 2];
            o0 += v0.w * w2r[4 * m + 3]; o1 += v1.w * w2r[4 * m + 3];
        }
        h[n0 * H + lane] = o0;   // no trailing silu in node model
        h[n1 * H + lane] = o1;
        __syncthreads();
    }
}

// ---------------- node decoder: h = (silu(h@W1+b1)@W2+b2) * node_mask ----
__global__ __launch_bounds__(64, 4) void k_dec(
        float* __restrict__ h, const float* __restrict__ nmask,
        const float* __restrict__ W1, const float* __restrict__ b1,
        const float* __restrict__ W2, const float* __restrict__ b2) {
    const int lane = threadIdx.x;
    float w1r[H], w2r[H];
#pragma unroll
    for (int k = 0; k < H; ++k) w1r[k] = W1[k * H + lane];
#pragma unroll
    for (int k = 0; k < H; ++k) w2r[k] = W2[k * H + lane];
    const float bias1 = b1[lane], bias2 = b2[lane];

    __shared__ __align__(16) float xb[2][64];
    __shared__ __align__(16) float tb[2][64];

    const int base = blockIdx.x * NPB;
    for (int p = 0; p < NPB; p += 2) {
        const int n0 = base + p, n1 = n0 + 1;
        xb[0][lane] = h[n0 * H + lane];
        xb[1][lane] = h[n1 * H + lane];
        __syncthreads();
        float a0 = bias1, a1 = bias1;
        const float4* x0 = (const float4*)(&xb[0][0]);
        const float4* x1 = (const float4*)(&xb[1][0]);
#pragma unroll
        for (int m = 0; m < 16; ++m) {
            float4 v0 = x0[m], v1 = x1[m];
            a0 += v0.x * w1r[4 * m + 0]; a1 += v1.x * w1r[4 * m + 0];
            a0 += v0.y * w1r[4 * m + 1]; a1 += v1.y * w1r[4 * m + 1];
            a0 += v0.z * w1r[4 * m + 2]; a1 += v1.z * w1r[4 * m + 2];
            a0 += v0.w * w1r[4 * m + 3]; a1 += v1.w * w1r[4 * m + 3];
        }
        float s0 = silu_f(a0), s1 = silu_f(a1);
        __syncthreads();
        tb[0][lane] = s0; tb[1][lane] = s1;
        __syncthreads();
        float o0 = bias2, o1 = bias2;
        const float4* q0 = (const float4*)(&tb[0][0]);
        const float4* q1 = (const float4*)(&tb[1][0]);
#pragma unroll
        for (int m = 0; m < 16; ++m) {
            float4 v0 = q0[m], v1 = q1[m];
            o0 += v0.x * w2r[4 * m + 0]; o1 += v1.x * w2r[4 * m + 0];
            o0 += v0.y * w2r[4 * m + 1]; o1 += v1.y * w2r[4 * m + 1];
            o0 += v0.z * w2r[4 * m + 2]; o1 += v1.z * w2r[4 * m + 2];
            o0 += v0.w * w2r[4 * m + 3]; o1 += v1.w * w2r[4 * m + 3];
        }
        h[n0 * H + lane] = o0 * nmask[n0];
        h[n1 * H + lane] = o1 * nmask[n1];
        __syncthreads();
    }
}

// ---------------- pool + graph decoder + signed reaction aggregation -----
__global__ __launch_bounds__(64) void k_graph(
        const float* __restrict__ h, const int* __restrict__ rid,
        const float* __restrict__ rsign,
        const float* __restrict__ W1, const float* __restrict__ b1,
        const float* __restrict__ W2, const float* __restrict__ b2,
        float* __restrict__ pred) {
    const int g = blockIdx.x;
    const int lane = threadIdx.x;
    float hgv = 0.0f;
#pragma unroll
    for (int m = 0; m < NN_PER_G; ++m)
        hgv += h[(g * NN_PER_G + m) * H + lane];
    __shared__ __align__(16) float hgs[64];
    hgs[lane] = hgv;
    __syncthreads();
    float acc = b1[lane];
#pragma unroll
    for (int k = 0; k < H; ++k)
        acc += hgs[k] * W1[k * H + lane];
    float part = silu_f(acc) * W2[lane];
#pragma unroll
    for (int off = 32; off > 0; off >>= 1)
        part += __shfl_down(part, off);
    if (lane == 0)
        atomAddF(&pred[rid[g]], (part + b2[0]) * rsign[g]);
}

extern "C" void kernel_launch(void* const* d_in, const int* in_sizes, int n_in,
                              void* d_out, int out_size, void* d_ws, size_t ws_size,
                              hipStream_t stream) {
    const float* h0      = (const float*)d_in[0];
    const float* pos     = (const float*)d_in[1];
    const int*   edges   = (const int*)d_in[2];
    const float* nmask   = (const float*)d_in[3];
    const float* emask   = (const float*)d_in[4];
    const int*   rid     = (const int*)d_in[5];
    const float* rsign   = (const float*)d_in[6];
    const float* emb_w   = (const float*)d_in[7];
    const float* emb_b   = (const float*)d_in[8];
    const float* edge_w1 = (const float*)d_in[9];
    const float* edge_b1 = (const float*)d_in[10];
    const float* edge_w2 = (const float*)d_in[11];
    const float* edge_b2 = (const float*)d_in[12];
    const float* node_w1 = (const float*)d_in[13];
    const float* node_b1 = (const float*)d_in[14];
    const float* node_w2 = (const float*)d_in[15];
    const float* node_b2 = (const float*)d_in[16];
    const float* dec_w1  = (const float*)d_in[17];
    const float* dec_b1  = (const float*)d_in[18];
    const float* dec_w2  = (const float*)d_in[19];
    const float* dec_b2  = (const float*)d_in[20];
    const float* g_w1    = (const float*)d_in[21];
    const float* g_b1    = (const float*)d_in[22];
    const float* g_w2    = (const float*)d_in[23];
    const float* g_b2    = (const float*)d_in[24];

    float* h      = (float*)d_ws;            // N*H
    float* agg    = h + N_NODES * H;         // N*H
    float* radial = agg + N_NODES * H;       // E
    float* PA     = radial + N_EDGES;        // N*H
    float* PB     = PA + N_NODES * H;        // N*H
    float* pred   = (float*)d_out;

    hipMemsetAsync(d_out, 0, R_REACT * sizeof(float), stream);
    k_embed<<<(N_NODES * H) / 256, 256, 0, stream>>>(h0, emb_w, emb_b, h, agg);
    k_radial<<<N_EDGES / 256, 256, 0, stream>>>(edges, pos, radial);

    for (int i = 0; i < L_LAYERS; ++i) {
        k_nodeproj<<<N_NODES / NPB, 64, 0, stream>>>(
            h, edge_w1 + i * EIN * H, edge_b1 + i * H, PA, PB);
        k_edge4<<<N_EDGES / (16 * 4 * TPW), 256, 0, stream>>>(
            PA, PB, radial, edges, emask,
            edge_w1 + i * EIN * H,
            edge_w2 + i * H * H, edge_b2 + i * H, agg);
        k_node<<<N_NODES / NPB, 64, 0, stream>>>(
            h, agg, h0,
            node_w1 + i * NIN * H, node_b1 + i * H,
            node_w2 + i * H * H,   node_b2 + i * H);
    }
    k_dec<<<N_NODES / NPB, 64, 0, stream>>>(h, nmask, dec_w1, dec_b1, dec_w2, dec_b2);
    k_graph<<<G_GRAPHS, 64, 0, stream>>>(h, rid, rsign, g_w1, g_b1, g_w2, g_b2, pred);
}